// Round 1
// baseline (635.704 us; speedup 1.0000x reference)
//
#include <hip/hip_runtime.h>
#include <stdint.h>
#include <stddef.h>

#define N_NODES 200000
#define N_EDGES 800000
#define NREL 16
#define NBASES 8

// ---- workspace layout (bytes) ----
#define WS_HIST    0         // 16 ints  (edge-message count per relation, = 2*edges)
#define WS_CURSOR  64        // 16 ints
#define WS_START   128       // 17 ints  (bucket starts, start[16] = end)
#define WS_WT      512       // 17*64*64 uint16 bf16, layout Wt[r][e][d]
#define WS_TILEREL 139776    // MAXTILES uint8
#define WS_RECS    262144    // MAXTILES*16 int2 (src,tgt)
#define MAXTILES   112520    // ceil((200000 + 1600000 + 16*16)/16) + slack
#define MAXRECS    (MAXTILES * 16)

typedef __attribute__((ext_vector_type(8))) short short8b;
typedef __attribute__((ext_vector_type(4))) float float4v;

__device__ __forceinline__ short f32_bf16(float f) {
  uint32_t u = __builtin_bit_cast(uint32_t, f);
  uint32_t r = u + 0x7FFFu + ((u >> 16) & 1u);
  return (short)(uint16_t)(r >> 16);
}

// W^T table: Wt[r][e][d] = bf16( sum_b att[r][b] * bases[b][d][e] )
__global__ __launch_bounds__(256) void k_wprep(const float* __restrict__ bases,
                                               const float* __restrict__ att,
                                               uint16_t* __restrict__ Wt) {
  int i = blockIdx.x * 256 + threadIdx.x;
  if (i >= 17 * 64 * 64) return;
  int r = i >> 12;          // /4096
  int e = (i >> 6) & 63;
  int d = i & 63;
  float acc = 0.f;
  for (int b = 0; b < NBASES; ++b)
    acc += att[r * NBASES + b] * bases[b * 4096 + d * 64 + e];
  Wt[i] = (uint16_t)f32_bf16(acc);
}

__global__ __launch_bounds__(256) void k_hist(const int* __restrict__ et,
                                              int* __restrict__ hist, int nE) {
  __shared__ int lh[NREL];
  if (threadIdx.x < NREL) lh[threadIdx.x] = 0;
  __syncthreads();
  int i = blockIdx.x * 256 + threadIdx.x;
  if (i < nE) atomicAdd(&lh[et[i]], 2);   // two messages per edge, same bucket
  __syncthreads();
  if (threadIdx.x < NREL && lh[threadIdx.x] > 0)
    atomicAdd(&hist[threadIdx.x], lh[threadIdx.x]);
}

__global__ __launch_bounds__(256) void k_prefix(const int* __restrict__ hist,
                                                int* __restrict__ cursor,
                                                int* __restrict__ start,
                                                uint8_t* __restrict__ tileRel,
                                                int nN, int maxTiles) {
  __shared__ int s_start[17];
  if (threadIdx.x == 0) {
    int base = nN;                       // [0, nN) = self-loop bucket (rel 16)
    for (int r = 0; r < NREL; ++r) {
      s_start[r] = base;
      cursor[r] = base;
      start[r] = base;
      base = (base + hist[r] + 15) & ~15;  // 16-aligned bucket boundaries
    }
    s_start[16] = base;
    start[16] = base;
  }
  __syncthreads();
  int endp = s_start[16];
  for (int t = threadIdx.x; t < maxTiles; t += 256) {
    int p = t * 16;
    uint8_t r;
    if (p < nN) r = 16;                  // self bucket
    else if (p >= endp) r = 255;         // past all records
    else {
      int q = 0;
      for (int k = 1; k < NREL; ++k) if (p >= s_start[k]) q = k;
      r = (uint8_t)q;
    }
    tileRel[t] = r;
  }
}

__global__ __launch_bounds__(256) void k_scatter(const int* __restrict__ src,
                                                 const int* __restrict__ tgt,
                                                 const int* __restrict__ et,
                                                 const int* __restrict__ mask,
                                                 int2* __restrict__ recs,
                                                 int* __restrict__ cursor,
                                                 int nE, int nN) {
  __shared__ int lh[NREL];
  __shared__ int lbase[NREL];
  if (threadIdx.x < NREL) lh[threadIdx.x] = 0;
  __syncthreads();
  int i = blockIdx.x * 256 + threadIdx.x;
  int r = 0, loff = 0;
  bool isEdge = (i < nE);
  if (isEdge) {
    r = et[i];
    loff = atomicAdd(&lh[r], 2);
  }
  __syncthreads();
  if (threadIdx.x < NREL)
    lbase[threadIdx.x] = (lh[threadIdx.x] > 0) ? atomicAdd(&cursor[threadIdx.x], lh[threadIdx.x]) : 0;
  __syncthreads();
  if (isEdge) {
    int pos = lbase[r] + loff;           // even, 16B aligned
    int s = src[i], t = tgt[i];
    *(int4*)(recs + pos) = make_int4(s, t, t, s);  // (u->v) and (v->u)
  }
  if (i < nN) {
    recs[i] = (mask[i] != 0) ? make_int2(i, i) : make_int2(-1, -1);
  }
}

// one wave per 16-message tile, 4 tiles per wave (lazy B reload)
__global__ __launch_bounds__(256) void k_compute(const float* __restrict__ x,
                                                 const int2* __restrict__ recs,
                                                 const uint16_t* __restrict__ Wt,
                                                 const uint8_t* __restrict__ tileRel,
                                                 float* __restrict__ out,
                                                 int ntiles) {
  const int lane = threadIdx.x & 63;
  const int quad = lane >> 4;
  const int m16 = lane & 15;
  const int wave = blockIdx.x * 4 + (threadIdx.x >> 6);
  const int t0 = wave * 4;

  int curRel = -1;
  short8b bfrag[4][2];

  for (int it = 0; it < 4; ++it) {
    int t = t0 + it;
    if (t >= ntiles) return;
    int rel = tileRel[t];
    if (rel == 255) return;              // tiles past the end are contiguous

    if (rel != curRel) {
      curRel = rel;
      // B[k][n] for k-step kt: element j = Wt[rel][nt*16+n][kt*32+quad*8+j]
      const uint16_t* wbase = Wt + (size_t)rel * 4096;
      for (int nt = 0; nt < 4; ++nt)
        for (int kt = 0; kt < 2; ++kt)
          bfrag[nt][kt] = *(const short8b*)(wbase + (size_t)(nt * 16 + m16) * 64 + kt * 32 + quad * 8);
    }

    int2 rec = recs[t * 16 + m16];       // record for row m16 (broadcast across quads)
    int u = rec.x < 0 ? 0 : rec.x;

    // A[m][k]: k-step0 -> x[u][quad*8 + j], k-step1 -> x[u][32 + quad*8 + j]
    const float* xp = x + (size_t)u * 64 + quad * 8;
    float4v q0 = *(const float4v*)(xp);
    float4v q1 = *(const float4v*)(xp + 4);
    float4v q2 = *(const float4v*)(xp + 32);
    float4v q3 = *(const float4v*)(xp + 36);
    short8b a0, a1;
    a0[0] = f32_bf16(q0[0]); a0[1] = f32_bf16(q0[1]); a0[2] = f32_bf16(q0[2]); a0[3] = f32_bf16(q0[3]);
    a0[4] = f32_bf16(q1[0]); a0[5] = f32_bf16(q1[1]); a0[6] = f32_bf16(q1[2]); a0[7] = f32_bf16(q1[3]);
    a1[0] = f32_bf16(q2[0]); a1[1] = f32_bf16(q2[1]); a1[2] = f32_bf16(q2[2]); a1[3] = f32_bf16(q2[3]);
    a1[4] = f32_bf16(q3[0]); a1[5] = f32_bf16(q3[1]); a1[6] = f32_bf16(q3[2]); a1[7] = f32_bf16(q3[3]);

    float4v acc[4];
    for (int nt = 0; nt < 4; ++nt) { acc[nt][0] = 0.f; acc[nt][1] = 0.f; acc[nt][2] = 0.f; acc[nt][3] = 0.f; }
    for (int nt = 0; nt < 4; ++nt) {
      acc[nt] = __builtin_amdgcn_mfma_f32_16x16x32_bf16(a0, bfrag[nt][0], acc[nt], 0, 0, 0);
      acc[nt] = __builtin_amdgcn_mfma_f32_16x16x32_bf16(a1, bfrag[nt][1], acc[nt], 0, 0, 0);
    }

    // C/D layout: col = lane&15, row = quad*4 + reg
    int tg[4];
    for (int reg = 0; reg < 4; ++reg)
      tg[reg] = __shfl(rec.y, quad * 4 + reg, 64);
    for (int reg = 0; reg < 4; ++reg) {
      if (tg[reg] < 0) continue;
      float* op = out + (size_t)tg[reg] * 64 + m16;
      for (int nt = 0; nt < 4; ++nt)
        __hip_atomic_fetch_add(op + nt * 16, acc[nt][reg], __ATOMIC_RELAXED, __HIP_MEMORY_SCOPE_AGENT);
    }
  }
}

extern "C" void kernel_launch(void* const* d_in, const int* in_sizes, int n_in,
                              void* d_out, int out_size, void* d_ws, size_t ws_size,
                              hipStream_t stream) {
  const float* x      = (const float*)d_in[0];
  const int*   mask   = (const int*)d_in[1];
  const int*   src    = (const int*)d_in[2];
  const int*   tgt    = (const int*)d_in[3];
  const int*   et     = (const int*)d_in[4];
  const float* bases  = (const float*)d_in[5];
  const float* att    = (const float*)d_in[6];
  float* out = (float*)d_out;

  char* ws = (char*)d_ws;
  int*      hist    = (int*)(ws + WS_HIST);
  int*      cursor  = (int*)(ws + WS_CURSOR);
  int*      start   = (int*)(ws + WS_START);
  uint16_t* Wt      = (uint16_t*)(ws + WS_WT);
  uint8_t*  tileRel = (uint8_t*)(ws + WS_TILEREL);
  int2*     recs    = (int2*)(ws + WS_RECS);

  hipMemsetAsync(out, 0, (size_t)N_NODES * 64 * sizeof(float), stream);
  hipMemsetAsync(ws, 0, 512, stream);
  hipMemsetAsync(recs, 0xFF, (size_t)MAXRECS * sizeof(int2), stream);

  k_wprep<<<(17 * 64 * 64 + 255) / 256, 256, 0, stream>>>(bases, att, Wt);
  k_hist<<<(N_EDGES + 255) / 256, 256, 0, stream>>>(et, hist, N_EDGES);
  k_prefix<<<1, 256, 0, stream>>>(hist, cursor, start, tileRel, N_NODES, MAXTILES);
  k_scatter<<<(N_EDGES + 255) / 256, 256, 0, stream>>>(src, tgt, et, mask, recs, cursor, N_EDGES, N_NODES);
  k_compute<<<(MAXTILES + 15) / 16, 256, 0, stream>>>(x, recs, Wt, tileRel, out, MAXTILES);
}

// Round 2
// 477.076 us; speedup vs baseline: 1.3325x; 1.3325x over previous
//
#include <hip/hip_runtime.h>
#include <stdint.h>
#include <stddef.h>

#define N_NODES 200000
#define N_EDGES 800000
#define NREL 16
#define NBASES 8

typedef __attribute__((ext_vector_type(8))) short short8b;
typedef __attribute__((ext_vector_type(4))) float float4v;

__device__ __forceinline__ short f32_bf16(float f) {
  uint32_t u = __builtin_bit_cast(uint32_t, f);
  uint32_t r = u + 0x7FFFu + ((u >> 16) & 1u);
  return (short)(uint16_t)(r >> 16);
}
__device__ __forceinline__ float bf2f(uint16_t h) {
  return __builtin_bit_cast(float, (uint32_t)h << 16);
}

// ============================ shared: W table ============================
// Wt[r][e][d] = bf16( sum_b att[r][b] * bases[b][d][e] )   (W transposed)
__global__ __launch_bounds__(256) void k_wprep(const float* __restrict__ bases,
                                               const float* __restrict__ att,
                                               uint16_t* __restrict__ Wt) {
  int i = blockIdx.x * 256 + threadIdx.x;
  if (i >= 17 * 64 * 64) return;
  int r = i >> 12;
  int e = (i >> 6) & 63;
  int d = i & 63;
  float acc = 0.f;
  for (int b = 0; b < NBASES; ++b)
    acc += att[r * NBASES + b] * bases[b * 4096 + d * 64 + e];
  Wt[i] = (uint16_t)f32_bf16(acc);
}

// ======================================================================
// NEW PATH: two-phase target-sorted (no output atomics)
// ======================================================================
#define MAXTILES 112528
#define MAXRECS  (MAXTILES * 16)
#define WS_CNTR    0          // 32 int
#define WS_RCUR    128        // 32 int
#define WS_RSTART  256        // 32 int (0..17 used)
#define WS_GCUR    384        // 1 int
#define WS_WT      512        // 17*64*64 u16 -> ends 139776
#define WS_TILEREL 139776     // MAXTILES u8 -> ends 252304 (pad to 252416)
#define WS_CNTV    252416     // 200000 int
#define WS_VSTART  1052416    // 200000 int
#define WS_VCUR    1852416    // 200000 int
#define WS_RECS    2652416    // MAXRECS int2 -> ends 17056000 (pad to 17056128)
#define WS_MSG     17056128   // MAXRECS * 64 u16 rows
#define WS_TOTAL   (WS_MSG + (size_t)MAXRECS * 128)   // ~247.5 MB

__global__ __launch_bounds__(256) void k_count(const int* __restrict__ src,
                                               const int* __restrict__ tgt,
                                               const int* __restrict__ et,
                                               const int* __restrict__ mask,
                                               int* __restrict__ cntr,
                                               int* __restrict__ cntv,
                                               int nE, int nN) {
  __shared__ int lh[NREL + 1];
  if (threadIdx.x <= NREL) lh[threadIdx.x] = 0;
  __syncthreads();
  int i = blockIdx.x * 256 + threadIdx.x;
  if (i < nE) {
    atomicAdd(&lh[et[i]], 2);
    atomicAdd(&cntv[tgt[i]], 1);
    atomicAdd(&cntv[src[i]], 1);
  }
  if (i < nN && mask[i]) {
    atomicAdd(&lh[NREL], 1);
    atomicAdd(&cntv[i], 1);
  }
  __syncthreads();
  if (threadIdx.x <= NREL && lh[threadIdx.x])
    atomicAdd(&cntr[threadIdx.x], lh[threadIdx.x]);
}

__global__ void k_bucket(const int* __restrict__ cntr,
                         int* __restrict__ rcur, int* __restrict__ rstart) {
  if (threadIdx.x == 0) {
    int base = 0;
    for (int r = 0; r <= NREL; ++r) {
      rstart[r] = base;
      rcur[r] = base;
      base = (base + cntr[r] + 15) & ~15;
    }
    rstart[NREL + 1] = base;
  }
}

// per-target contiguous segment allocation; block-local order preserved
__global__ __launch_bounds__(256) void k_vseg(const int* __restrict__ cntv,
                                              int* __restrict__ vstart,
                                              int* __restrict__ vcur,
                                              int* __restrict__ gcur, int nN) {
  __shared__ int s[256];
  __shared__ int s_base;
  int v = blockIdx.x * 256 + threadIdx.x;
  int c = (v < nN) ? cntv[v] : 0;
  s[threadIdx.x] = c;
  __syncthreads();
  int incl = c;
  for (int off = 1; off < 256; off <<= 1) {
    int add = (threadIdx.x >= off) ? s[threadIdx.x - off] : 0;
    __syncthreads();
    incl += add;
    s[threadIdx.x] = incl;
    __syncthreads();
  }
  if (threadIdx.x == 255) s_base = atomicAdd(gcur, incl);
  __syncthreads();
  if (v < nN) {
    int st = s_base + incl - c;
    vstart[v] = st;
    vcur[v] = st;
  }
}

__global__ __launch_bounds__(256) void k_tilerel(const int* __restrict__ rstart,
                                                 uint8_t* __restrict__ tileRel,
                                                 int maxTiles) {
  __shared__ int s[NREL + 2];
  if (threadIdx.x < NREL + 2) s[threadIdx.x] = rstart[threadIdx.x];
  __syncthreads();
  int t = blockIdx.x * 256 + threadIdx.x;
  if (t >= maxTiles) return;
  int p = t * 16;
  uint8_t r = 255;
  if (p < s[NREL + 1]) {
    int q = 0;
    for (int k = 1; k <= NREL; ++k)
      if (p >= s[k]) q = k;
    r = (uint8_t)q;
  }
  tileRel[t] = r;
}

__global__ __launch_bounds__(256) void k_records(const int* __restrict__ src,
                                                 const int* __restrict__ tgt,
                                                 const int* __restrict__ et,
                                                 const int* __restrict__ mask,
                                                 int2* __restrict__ recs,
                                                 int* __restrict__ rcur,
                                                 int* __restrict__ vcur,
                                                 int nE, int nN) {
  __shared__ int lh[NREL + 1], lbase[NREL + 1];
  if (threadIdx.x <= NREL) lh[threadIdx.x] = 0;
  __syncthreads();
  int i = blockIdx.x * 256 + threadIdx.x;
  bool isE = i < nE;
  bool isN = (i < nN) && mask[i];
  int r = 0, loff = 0, loffN = 0, s_ = 0, t_ = 0;
  if (isE) {
    r = et[i];
    s_ = src[i];
    t_ = tgt[i];
    loff = atomicAdd(&lh[r], 2);
  }
  if (isN) loffN = atomicAdd(&lh[NREL], 1);
  __syncthreads();
  if (threadIdx.x <= NREL)
    lbase[threadIdx.x] = lh[threadIdx.x] ? atomicAdd(&rcur[threadIdx.x], lh[threadIdx.x]) : 0;
  __syncthreads();
  if (isE) {
    int pos = lbase[r] + loff;            // even -> 16B aligned
    int o1 = atomicAdd(&vcur[t_], 1);     // msg (s_ -> t_)
    int o2 = atomicAdd(&vcur[s_], 1);     // msg (t_ -> s_)
    *(int4*)(recs + pos) = make_int4(s_, o1, t_, o2);
  }
  if (isN) {
    int pos = lbase[NREL] + loffN;
    int o = atomicAdd(&vcur[i], 1);
    recs[pos] = make_int2(i, o);
  }
}

// Phase A: relation-grouped MFMA, write bf16 message rows at target-sorted slots
__global__ __launch_bounds__(256) void k_phaseA(const float* __restrict__ x,
                                                const int2* __restrict__ recs,
                                                const uint16_t* __restrict__ Wt,
                                                const uint8_t* __restrict__ tileRel,
                                                uint16_t* __restrict__ msg,
                                                int ntiles) {
  __shared__ uint16_t s_m[4][16 * 72];   // +8 elem row pad
  __shared__ int s_slot[4][16];
  const int wid = threadIdx.x >> 6;
  const int lane = threadIdx.x & 63;
  const int quad = lane >> 4;
  const int m16 = lane & 15;
  const int t0 = (blockIdx.x * 4 + wid) * 4;

  int curRel = -1;
  short8b bfrag[4][2] = {};

  for (int it = 0; it < 4; ++it) {       // uniform trip count: barriers legal
    int t = t0 + it;
    int rel = (t < ntiles) ? (int)tileRel[t] : 255;
    bool valid = (rel != 255);

    if (valid && rel != curRel) {
      curRel = rel;
      const uint16_t* wbase = Wt + (size_t)rel * 4096;
      for (int nt = 0; nt < 4; ++nt)
        for (int kt = 0; kt < 2; ++kt)
          bfrag[nt][kt] = *(const short8b*)(wbase + (size_t)(nt * 16 + m16) * 64 + kt * 32 + quad * 8);
    }

    int2 rec = valid ? recs[t * 16 + m16] : make_int2(-1, -1);
    int u = rec.x < 0 ? 0 : rec.x;

    const float* xp = x + (size_t)u * 64 + quad * 8;
    float4v q0 = *(const float4v*)(xp);
    float4v q1 = *(const float4v*)(xp + 4);
    float4v q2 = *(const float4v*)(xp + 32);
    float4v q3 = *(const float4v*)(xp + 36);
    short8b a0, a1;
    a0[0] = f32_bf16(q0[0]); a0[1] = f32_bf16(q0[1]); a0[2] = f32_bf16(q0[2]); a0[3] = f32_bf16(q0[3]);
    a0[4] = f32_bf16(q1[0]); a0[5] = f32_bf16(q1[1]); a0[6] = f32_bf16(q1[2]); a0[7] = f32_bf16(q1[3]);
    a1[0] = f32_bf16(q2[0]); a1[1] = f32_bf16(q2[1]); a1[2] = f32_bf16(q2[2]); a1[3] = f32_bf16(q2[3]);
    a1[4] = f32_bf16(q3[0]); a1[5] = f32_bf16(q3[1]); a1[6] = f32_bf16(q3[2]); a1[7] = f32_bf16(q3[3]);

    float4v acc[4];
    for (int nt = 0; nt < 4; ++nt) { acc[nt][0] = 0.f; acc[nt][1] = 0.f; acc[nt][2] = 0.f; acc[nt][3] = 0.f; }
    for (int nt = 0; nt < 4; ++nt) {
      acc[nt] = __builtin_amdgcn_mfma_f32_16x16x32_bf16(a0, bfrag[nt][0], acc[nt], 0, 0, 0);
      acc[nt] = __builtin_amdgcn_mfma_f32_16x16x32_bf16(a1, bfrag[nt][1], acc[nt], 0, 0, 0);
    }

    // C/D: col(dim) = m16 + nt*16, row(message) = quad*4 + reg
    if (quad == 0) s_slot[wid][m16] = rec.y;
    for (int reg = 0; reg < 4; ++reg)
      for (int nt = 0; nt < 4; ++nt)
        s_m[wid][(quad * 4 + reg) * 72 + nt * 16 + m16] = (uint16_t)f32_bf16(acc[nt][reg]);
    __syncthreads();

    // 16 rows x 128 B, 8 lanes/row x 16 B
    for (int p = 0; p < 2; ++p) {
      int row = (lane >> 3) + p * 8;
      int slot = s_slot[wid][row];
      if (slot >= 0) {
        const uint16_t* lp = &s_m[wid][row * 72 + (lane & 7) * 8];
        int4 val = *(const int4*)lp;
        *(int4*)(msg + (size_t)slot * 64 + (lane & 7) * 8) = val;
      }
    }
    __syncthreads();
  }
}

// Phase B: per-target segmented sum (contiguous reads, single write, no atomics)
__global__ __launch_bounds__(256) void k_phaseB(const uint16_t* __restrict__ msg,
                                                const int* __restrict__ cntv,
                                                const int* __restrict__ vstart,
                                                float* __restrict__ out, int nN) {
  int v = blockIdx.x * 16 + (threadIdx.x >> 4);
  int l = threadIdx.x & 15;
  if (v >= nN) return;
  int cnt = cntv[v];
  int base = vstart[v];
  float a0 = 0.f, a1 = 0.f, a2 = 0.f, a3 = 0.f;
  const uint16_t* mp = msg + (size_t)base * 64 + l * 4;
  int j = 0;
  for (; j + 2 <= cnt; j += 2) {
    ushort4 h0 = *(const ushort4*)(mp + (size_t)j * 64);
    ushort4 h1 = *(const ushort4*)(mp + (size_t)(j + 1) * 64);
    a0 += bf2f(h0.x) + bf2f(h1.x);
    a1 += bf2f(h0.y) + bf2f(h1.y);
    a2 += bf2f(h0.z) + bf2f(h1.z);
    a3 += bf2f(h0.w) + bf2f(h1.w);
  }
  if (j < cnt) {
    ushort4 h = *(const ushort4*)(mp + (size_t)j * 64);
    a0 += bf2f(h.x); a1 += bf2f(h.y); a2 += bf2f(h.z); a3 += bf2f(h.w);
  }
  float4 o = make_float4(a0, a1, a2, a3);
  *(float4*)(out + (size_t)v * 64 + l * 4) = o;
}

// ======================================================================
// FALLBACK PATH (round-1, atomic scatter) — used only if ws_size too small
// ======================================================================
#define F_WS_HIST    0
#define F_WS_CURSOR  64
#define F_WS_START   128
#define F_WS_WT      512
#define F_WS_TILEREL 139776
#define F_WS_RECS    262144
#define F_MAXTILES   112520
#define F_MAXRECS    (F_MAXTILES * 16)

__global__ __launch_bounds__(256) void f_hist(const int* __restrict__ et,
                                              int* __restrict__ hist, int nE) {
  __shared__ int lh[NREL];
  if (threadIdx.x < NREL) lh[threadIdx.x] = 0;
  __syncthreads();
  int i = blockIdx.x * 256 + threadIdx.x;
  if (i < nE) atomicAdd(&lh[et[i]], 2);
  __syncthreads();
  if (threadIdx.x < NREL && lh[threadIdx.x] > 0)
    atomicAdd(&hist[threadIdx.x], lh[threadIdx.x]);
}

__global__ __launch_bounds__(256) void f_prefix(const int* __restrict__ hist,
                                                int* __restrict__ cursor,
                                                int* __restrict__ start,
                                                uint8_t* __restrict__ tileRel,
                                                int nN, int maxTiles) {
  __shared__ int s_start[17];
  if (threadIdx.x == 0) {
    int base = nN;
    for (int r = 0; r < NREL; ++r) {
      s_start[r] = base;
      cursor[r] = base;
      start[r] = base;
      base = (base + hist[r] + 15) & ~15;
    }
    s_start[16] = base;
    start[16] = base;
  }
  __syncthreads();
  int endp = s_start[16];
  for (int t = threadIdx.x; t < maxTiles; t += 256) {
    int p = t * 16;
    uint8_t r;
    if (p < nN) r = 16;
    else if (p >= endp) r = 255;
    else {
      int q = 0;
      for (int k = 1; k < NREL; ++k) if (p >= s_start[k]) q = k;
      r = (uint8_t)q;
    }
    tileRel[t] = r;
  }
}

__global__ __launch_bounds__(256) void f_scatter(const int* __restrict__ src,
                                                 const int* __restrict__ tgt,
                                                 const int* __restrict__ et,
                                                 const int* __restrict__ mask,
                                                 int2* __restrict__ recs,
                                                 int* __restrict__ cursor,
                                                 int nE, int nN) {
  __shared__ int lh[NREL];
  __shared__ int lbase[NREL];
  if (threadIdx.x < NREL) lh[threadIdx.x] = 0;
  __syncthreads();
  int i = blockIdx.x * 256 + threadIdx.x;
  int r = 0, loff = 0;
  bool isEdge = (i < nE);
  if (isEdge) {
    r = et[i];
    loff = atomicAdd(&lh[r], 2);
  }
  __syncthreads();
  if (threadIdx.x < NREL)
    lbase[threadIdx.x] = (lh[threadIdx.x] > 0) ? atomicAdd(&cursor[threadIdx.x], lh[threadIdx.x]) : 0;
  __syncthreads();
  if (isEdge) {
    int pos = lbase[r] + loff;
    int s = src[i], t = tgt[i];
    *(int4*)(recs + pos) = make_int4(s, t, t, s);
  }
  if (i < nN) {
    recs[i] = (mask[i] != 0) ? make_int2(i, i) : make_int2(-1, -1);
  }
}

__global__ __launch_bounds__(256) void f_compute(const float* __restrict__ x,
                                                 const int2* __restrict__ recs,
                                                 const uint16_t* __restrict__ Wt,
                                                 const uint8_t* __restrict__ tileRel,
                                                 float* __restrict__ out,
                                                 int ntiles) {
  const int lane = threadIdx.x & 63;
  const int quad = lane >> 4;
  const int m16 = lane & 15;
  const int wave = blockIdx.x * 4 + (threadIdx.x >> 6);
  const int t0 = wave * 4;

  int curRel = -1;
  short8b bfrag[4][2] = {};

  for (int it = 0; it < 4; ++it) {
    int t = t0 + it;
    if (t >= ntiles) return;
    int rel = tileRel[t];
    if (rel == 255) return;

    if (rel != curRel) {
      curRel = rel;
      const uint16_t* wbase = Wt + (size_t)rel * 4096;
      for (int nt = 0; nt < 4; ++nt)
        for (int kt = 0; kt < 2; ++kt)
          bfrag[nt][kt] = *(const short8b*)(wbase + (size_t)(nt * 16 + m16) * 64 + kt * 32 + quad * 8);
    }

    int2 rec = recs[t * 16 + m16];
    int u = rec.x < 0 ? 0 : rec.x;

    const float* xp = x + (size_t)u * 64 + quad * 8;
    float4v q0 = *(const float4v*)(xp);
    float4v q1 = *(const float4v*)(xp + 4);
    float4v q2 = *(const float4v*)(xp + 32);
    float4v q3 = *(const float4v*)(xp + 36);
    short8b a0, a1;
    a0[0] = f32_bf16(q0[0]); a0[1] = f32_bf16(q0[1]); a0[2] = f32_bf16(q0[2]); a0[3] = f32_bf16(q0[3]);
    a0[4] = f32_bf16(q1[0]); a0[5] = f32_bf16(q1[1]); a0[6] = f32_bf16(q1[2]); a0[7] = f32_bf16(q1[3]);
    a1[0] = f32_bf16(q2[0]); a1[1] = f32_bf16(q2[1]); a1[2] = f32_bf16(q2[2]); a1[3] = f32_bf16(q2[3]);
    a1[4] = f32_bf16(q3[0]); a1[5] = f32_bf16(q3[1]); a1[6] = f32_bf16(q3[2]); a1[7] = f32_bf16(q3[3]);

    float4v acc[4];
    for (int nt = 0; nt < 4; ++nt) { acc[nt][0] = 0.f; acc[nt][1] = 0.f; acc[nt][2] = 0.f; acc[nt][3] = 0.f; }
    for (int nt = 0; nt < 4; ++nt) {
      acc[nt] = __builtin_amdgcn_mfma_f32_16x16x32_bf16(a0, bfrag[nt][0], acc[nt], 0, 0, 0);
      acc[nt] = __builtin_amdgcn_mfma_f32_16x16x32_bf16(a1, bfrag[nt][1], acc[nt], 0, 0, 0);
    }

    int tg[4];
    for (int reg = 0; reg < 4; ++reg)
      tg[reg] = __shfl(rec.y, quad * 4 + reg, 64);
    for (int reg = 0; reg < 4; ++reg) {
      if (tg[reg] < 0) continue;
      float* op = out + (size_t)tg[reg] * 64 + m16;
      for (int nt = 0; nt < 4; ++nt)
        __hip_atomic_fetch_add(op + nt * 16, acc[nt][reg], __ATOMIC_RELAXED, __HIP_MEMORY_SCOPE_AGENT);
    }
  }
}

// ======================================================================
extern "C" void kernel_launch(void* const* d_in, const int* in_sizes, int n_in,
                              void* d_out, int out_size, void* d_ws, size_t ws_size,
                              hipStream_t stream) {
  const float* x     = (const float*)d_in[0];
  const int*   mask  = (const int*)d_in[1];
  const int*   src   = (const int*)d_in[2];
  const int*   tgt   = (const int*)d_in[3];
  const int*   et    = (const int*)d_in[4];
  const float* bases = (const float*)d_in[5];
  const float* att   = (const float*)d_in[6];
  float* out = (float*)d_out;
  char* ws = (char*)d_ws;

  if (ws_size >= WS_TOTAL) {
    // ---------- two-phase target-sorted path ----------
    int*      cntr    = (int*)(ws + WS_CNTR);
    int*      rcur    = (int*)(ws + WS_RCUR);
    int*      rstart  = (int*)(ws + WS_RSTART);
    int*      gcur    = (int*)(ws + WS_GCUR);
    uint16_t* Wt      = (uint16_t*)(ws + WS_WT);
    uint8_t*  tileRel = (uint8_t*)(ws + WS_TILEREL);
    int*      cntv    = (int*)(ws + WS_CNTV);
    int*      vstart  = (int*)(ws + WS_VSTART);
    int*      vcur    = (int*)(ws + WS_VCUR);
    int2*     recs    = (int2*)(ws + WS_RECS);
    uint16_t* msg     = (uint16_t*)(ws + WS_MSG);

    hipMemsetAsync(ws, 0, 512, stream);
    hipMemsetAsync(cntv, 0, N_NODES * sizeof(int), stream);
    hipMemsetAsync(recs, 0xFF, (size_t)MAXRECS * sizeof(int2), stream);

    k_wprep<<<(17 * 64 * 64 + 255) / 256, 256, 0, stream>>>(bases, att, Wt);
    k_count<<<(N_EDGES + 255) / 256, 256, 0, stream>>>(src, tgt, et, mask, cntr, cntv, N_EDGES, N_NODES);
    k_bucket<<<1, 64, 0, stream>>>(cntr, rcur, rstart);
    k_vseg<<<(N_NODES + 255) / 256, 256, 0, stream>>>(cntv, vstart, vcur, gcur, N_NODES);
    k_tilerel<<<(MAXTILES + 255) / 256, 256, 0, stream>>>(rstart, tileRel, MAXTILES);
    k_records<<<(N_EDGES + 255) / 256, 256, 0, stream>>>(src, tgt, et, mask, recs, rcur, vcur, N_EDGES, N_NODES);
    k_phaseA<<<(MAXTILES + 15) / 16, 256, 0, stream>>>(x, recs, Wt, tileRel, msg, MAXTILES);
    k_phaseB<<<(N_NODES + 15) / 16, 256, 0, stream>>>(msg, cntv, vstart, out, N_NODES);
  } else {
    // ---------- fallback: round-1 atomic path ----------
    int*      hist    = (int*)(ws + F_WS_HIST);
    int*      cursor  = (int*)(ws + F_WS_CURSOR);
    int*      start   = (int*)(ws + F_WS_START);
    uint16_t* Wt      = (uint16_t*)(ws + F_WS_WT);
    uint8_t*  tileRel = (uint8_t*)(ws + F_WS_TILEREL);
    int2*     recs    = (int2*)(ws + F_WS_RECS);

    hipMemsetAsync(out, 0, (size_t)N_NODES * 64 * sizeof(float), stream);
    hipMemsetAsync(ws, 0, 512, stream);
    hipMemsetAsync(recs, 0xFF, (size_t)F_MAXRECS * sizeof(int2), stream);

    k_wprep<<<(17 * 64 * 64 + 255) / 256, 256, 0, stream>>>(bases, att, Wt);
    f_hist<<<(N_EDGES + 255) / 256, 256, 0, stream>>>(et, hist, N_EDGES);
    f_prefix<<<1, 256, 0, stream>>>(hist, cursor, start, tileRel, N_NODES, F_MAXTILES);
    f_scatter<<<(N_EDGES + 255) / 256, 256, 0, stream>>>(src, tgt, et, mask, recs, cursor, N_EDGES, N_NODES);
    f_compute<<<(F_MAXTILES + 15) / 16, 256, 0, stream>>>(x, recs, Wt, tileRel, out, F_MAXTILES);
  }
}